// Round 2
// baseline (318.478 us; speedup 1.0000x reference)
//
#include <hip/hip_runtime.h>
#include <stdint.h>

using bf16x8 = __attribute__((ext_vector_type(8))) __bf16;
using f32x4  = __attribute__((ext_vector_type(4))) float;
using u16x8  = __attribute__((ext_vector_type(8))) uint16_t;

#define S_LEN 4096
#define E_DIM 2048
#define D_DIM 128
#define H_NUM 16
#define G_NUM 4
#define QKV_N 3072
#define SCALE 0.08838834764831845f

__device__ inline float bf2f(uint16_t b) {
  union { uint32_t u; float f; } v; v.u = ((uint32_t)b) << 16; return v.f;
}
__device__ inline uint16_t f2bf(float f) {
  union { float f; uint32_t u; } v; v.f = f;
  uint32_t u = v.u + 0x7FFFu + ((v.u >> 16) & 1u);
  return (uint16_t)(u >> 16);
}
__device__ inline void gload_lds16(const void* g, void* l) {
  __builtin_amdgcn_global_load_lds((const __attribute__((address_space(1))) void*)g,
                                   (__attribute__((address_space(3))) void*)l, 16, 0, 0);
}

// ---------------- fp32 -> bf16 convert (8 elems/thread) ----------------
__global__ __launch_bounds__(256) void conv_f2b(const float* __restrict__ in,
                                                uint16_t* __restrict__ out) {
  const size_t i = ((size_t)blockIdx.x * 256 + threadIdx.x) * 8;
  float4 a = *(const float4*)(in + i);
  float4 b = *(const float4*)(in + i + 4);
  u16x8 o;
  o[0] = f2bf(a.x); o[1] = f2bf(a.y); o[2] = f2bf(a.z); o[3] = f2bf(a.w);
  o[4] = f2bf(b.x); o[5] = f2bf(b.y); o[6] = f2bf(b.z); o[7] = f2bf(b.w);
  *(u16x8*)(out + i) = o;
}

// ---------------- transpose fp32 -> bf16: out[c][r] = bf16(in[r][c]) ----------------
__global__ __launch_bounds__(256) void transpose_f2b(
    const float* __restrict__ in, uint16_t* __restrict__ out,
    int ldi, int ldo)
{
  __shared__ __align__(16) uint16_t tile[64][65];
  const int c0 = blockIdx.x * 64, r0 = blockIdx.y * 64;
  const int t = threadIdx.x;
#pragma unroll
  for (int i = 0; i < 16; ++i) {
    int idx = t + i * 256;
    int r = idx >> 6, c = idx & 63;
    tile[r][c] = f2bf(in[(size_t)(r0 + r) * ldi + c0 + c]);
  }
  __syncthreads();
#pragma unroll
  for (int i = 0; i < 16; ++i) {
    int idx = t + i * 256;
    int cc = idx >> 6, rr = idx & 63;
    out[(size_t)(c0 + cc) * ldo + r0 + rr] = tile[rr][cc];
  }
}

// ---------------- transpose bf16 -> bf16 (for V) ----------------
__global__ __launch_bounds__(256) void transpose_bf16(
    const uint16_t* __restrict__ in, uint16_t* __restrict__ out,
    int ldi, int ldo)
{
  __shared__ __align__(16) uint16_t tile[64][65];
  const int c0 = blockIdx.x * 64, r0 = blockIdx.y * 64;
  const int t = threadIdx.x;
#pragma unroll
  for (int i = 0; i < 16; ++i) {
    int idx = t + i * 256;
    int r = idx >> 6, c = idx & 63;
    tile[r][c] = in[(size_t)(r0 + r) * ldi + c0 + c];
  }
  __syncthreads();
#pragma unroll
  for (int i = 0; i < 16; ++i) {
    int idx = t + i * 256;
    int cc = idx >> 6, rr = idx & 63;
    out[(size_t)(c0 + cc) * ldo + r0 + rr] = tile[rr][cc];
  }
}

// ---------------- GEMM: C = A[M][K](bf16) * Bt[N][K]^T(bf16), f32 acc ----------------
// Cf != nullptr -> write fp32 to Cf, else bf16 to Cb.
__global__ __launch_bounds__(256) void gemm_bt(
    const uint16_t* __restrict__ A, const uint16_t* __restrict__ Bt,
    uint16_t* __restrict__ Cb, float* __restrict__ Cf, int M, int N, int K)
{
  __shared__ __align__(16) uint16_t sA[128 * 32];
  __shared__ __align__(16) uint16_t sB[128 * 32];
  const int m0 = blockIdx.x * 128, n0 = blockIdx.y * 128;
  const int tid = threadIdx.x, w = tid >> 6, lane = tid & 63;
  const int lr = lane & 15, lq = lane >> 4;
  const int wr = w >> 1, wc = w & 1;

  f32x4 acc[4][4];
#pragma unroll
  for (int i = 0; i < 4; ++i)
#pragma unroll
    for (int j = 0; j < 4; ++j) acc[i][j] = (f32x4){0.f, 0.f, 0.f, 0.f};

  const int nk = K >> 5;
  const int colb = (lane & 3) << 4;           // byte col within 64B row
  const int rbase0 = w * 32 + (lane >> 2);    // staging row for this lane
  const char* gA0 = (const char*)A + ((size_t)(m0 + rbase0) * K) * 2 + colb;
  const char* gA1 = (const char*)A + ((size_t)(m0 + rbase0 + 16) * K) * 2 + colb;
  const char* gB0 = (const char*)Bt + ((size_t)(n0 + rbase0) * K) * 2 + colb;
  const char* gB1 = (const char*)Bt + ((size_t)(n0 + rbase0 + 16) * K) * 2 + colb;
  char* lA0 = (char*)sA + (w * 2) * 1024;
  char* lA1 = (char*)sA + (w * 2 + 1) * 1024;
  char* lB0 = (char*)sB + (w * 2) * 1024;
  char* lB1 = (char*)sB + (w * 2 + 1) * 1024;

  for (int kt = 0; kt < nk; ++kt) {
    __syncthreads();
    const size_t ko = (size_t)kt * 64;  // 32 elems * 2B
    gload_lds16(gA0 + ko, lA0);
    gload_lds16(gA1 + ko, lA1);
    gload_lds16(gB0 + ko, lB0);
    gload_lds16(gB1 + ko, lB1);
    asm volatile("s_waitcnt vmcnt(0)" ::: "memory");
    __syncthreads();

    bf16x8 af[4], bfj[4];
#pragma unroll
    for (int i = 0; i < 4; ++i) af[i] = *(const bf16x8*)(sA + (wr * 64 + i * 16 + lr) * 32 + lq * 8);
#pragma unroll
    for (int j = 0; j < 4; ++j) bfj[j] = *(const bf16x8*)(sB + (wc * 64 + j * 16 + lr) * 32 + lq * 8);
#pragma unroll
    for (int i = 0; i < 4; ++i)
#pragma unroll
      for (int j = 0; j < 4; ++j)
        acc[i][j] = __builtin_amdgcn_mfma_f32_16x16x32_bf16(af[i], bfj[j], acc[i][j], 0, 0, 0);
  }

  if (Cf) {
#pragma unroll
    for (int i = 0; i < 4; ++i)
#pragma unroll
      for (int j = 0; j < 4; ++j)
#pragma unroll
        for (int r = 0; r < 4; ++r)
          Cf[(size_t)(m0 + wr * 64 + i * 16 + lq * 4 + r) * N + n0 + wc * 64 + j * 16 + lr] =
              acc[i][j][r];
  } else {
#pragma unroll
    for (int i = 0; i < 4; ++i)
#pragma unroll
      for (int j = 0; j < 4; ++j)
#pragma unroll
        for (int r = 0; r < 4; ++r)
          Cb[(size_t)(m0 + wr * 64 + i * 16 + lq * 4 + r) * N + n0 + wc * 64 + j * 16 + lr] =
              f2bf(acc[i][j][r]);
  }
}

// ---------------- RoPE + rearrange for q,k (cos/sin are fp32) ----------------
__global__ __launch_bounds__(256) void rope_qk(
    const uint16_t* __restrict__ qkv, const float* __restrict__ cosb,
    const float* __restrict__ sinb, uint16_t* __restrict__ q_r, uint16_t* __restrict__ k_r)
{
  const int idx = blockIdx.x * 256 + threadIdx.x;  // < 4096*1280
  const int s = idx / 1280;
  const int pp = idx - s * 1280;
  const int c0 = pp << 1;
  const uint32_t xp = *(const uint32_t*)(qkv + (size_t)s * QKV_N + c0);
  const float xe = bf2f((uint16_t)xp), xo = bf2f((uint16_t)(xp >> 16));
  const int dloc = c0 & 127;
  const int dd = dloc >> 1;
  const float cf = cosb[s * 64 + dd];
  const float sf = sinb[s * 64 + dd];
  float oe = xe * cf - xo * sf;
  float oo = xe * sf + xo * cf;
  uint16_t* dst;
  if (c0 < E_DIM) {
    oe *= SCALE; oo *= SCALE;                 // fold 1/sqrt(D) into q
    const int h = c0 >> 7;
    dst = q_r + ((size_t)h * S_LEN + s) * D_DIM + dloc;
  } else {
    const int g = (c0 - E_DIM) >> 7;
    dst = k_r + ((size_t)g * S_LEN + s) * D_DIM + dloc;
  }
  *(uint32_t*)dst = (uint32_t)f2bf(oe) | ((uint32_t)f2bf(oo) << 16);
}

// ---------------- flash attention, window [p-1024, p] ----------------
__global__ __launch_bounds__(256) void attn_kernel(
    const uint16_t* __restrict__ q_r, const uint16_t* __restrict__ k_r,
    const uint16_t* __restrict__ v_t, uint16_t* __restrict__ o_r)
{
  __shared__ __align__(16) uint16_t sK[64 * 128];   // [key][d]
  __shared__ __align__(16) uint16_t sVT[128 * 64];  // [d][key]
  __shared__ __align__(16) uint16_t sP[4][1024];    // per-wave [16][64]
  const int h = blockIdx.y, g = h >> 2;
  const int q0 = blockIdx.x * 64;
  const int tid = threadIdx.x, w = tid >> 6, lane = tid & 63;
  const int lr = lane & 15, lq = lane >> 4;

  bf16x8 aq[4];
  {
    const uint16_t* qb = q_r + ((size_t)h * S_LEN + q0 + w * 16 + lr) * D_DIM + lq * 8;
#pragma unroll
    for (int ks = 0; ks < 4; ++ks) aq[ks] = *(const bf16x8*)(qb + ks * 32);
  }
  f32x4 accO[8];
#pragma unroll
  for (int dt = 0; dt < 8; ++dt) accO[dt] = (f32x4){0.f, 0.f, 0.f, 0.f};
  float M[4], L[4];
#pragma unroll
  for (int r = 0; r < 4; ++r) { M[r] = -1e30f; L[r] = 0.f; }

  const int jstart = (q0 >= 1024) ? (q0 - 1024) : 0;
  const uint16_t* ksrc = k_r + ((size_t)g * S_LEN + jstart) * D_DIM;
  const uint16_t* vsrc = v_t + (size_t)g * D_DIM * S_LEN + jstart;
  const int vrow = (lane >> 3);          // 0..7 within an 8-row issue
  const int vcol = (lane & 7) << 4;      // byte col in 128B row

  for (int j0 = jstart; j0 < q0 + 64; j0 += 64) {
    __syncthreads();
#pragma unroll
    for (int it = 0; it < 4; ++it) {
      const int boff = (w * 4 + it) * 1024;
      gload_lds16((const char*)ksrc + boff + lane * 16, (char*)sK + boff);
    }
#pragma unroll
    for (int it = 0; it < 4; ++it) {
      const int rbase = (w * 4 + it) * 8 + vrow;
      gload_lds16((const char*)(vsrc + (size_t)rbase * S_LEN) + vcol,
                  (char*)sVT + (w * 4 + it) * 1024);
    }
    asm volatile("s_waitcnt vmcnt(0)" ::: "memory");
    __syncthreads();

    // QK^T : accS[ct] rows m=lq*4+r, cols j0+ct*16+lr
    f32x4 accS[4];
#pragma unroll
    for (int ct = 0; ct < 4; ++ct) {
      accS[ct] = (f32x4){0.f, 0.f, 0.f, 0.f};
#pragma unroll
      for (int ks = 0; ks < 4; ++ks) {
        bf16x8 bk = *(const bf16x8*)(sK + (ct * 16 + lr) * 128 + ks * 32 + lq * 8);
        accS[ct] = __builtin_amdgcn_mfma_f32_16x16x32_bf16(aq[ks], bk, accS[ct], 0, 0, 0);
      }
    }

    const int pbase = q0 + w * 16 + lq * 4;
    float alpha[4];
#pragma unroll
    for (int r = 0; r < 4; ++r) {
      const int p = pbase + r;
      float mx = -1e30f;
#pragma unroll
      for (int ct = 0; ct < 4; ++ct) {
        const int j = j0 + ct * 16 + lr;
        float sc = accS[ct][r];
        const bool ok = (j <= p) && (j + 1024 >= p);
        sc = ok ? sc : -1e30f;
        accS[ct][r] = sc;
        mx = fmaxf(mx, sc);
      }
#pragma unroll
      for (int off = 1; off < 16; off <<= 1) mx = fmaxf(mx, __shfl_xor(mx, off));
      const float Mn = fmaxf(M[r], mx);
      const float al = __expf(M[r] - Mn);
      float rs = 0.f;
#pragma unroll
      for (int ct = 0; ct < 4; ++ct) {
        const float pv = __expf(accS[ct][r] - Mn);
        accS[ct][r] = pv;
        rs += pv;
      }
#pragma unroll
      for (int off = 1; off < 16; off <<= 1) rs += __shfl_xor(rs, off);
      L[r] = L[r] * al + rs;
      M[r] = Mn;
      alpha[r] = al;
    }
#pragma unroll
    for (int dt = 0; dt < 8; ++dt)
#pragma unroll
      for (int r = 0; r < 4; ++r) accO[dt][r] *= alpha[r];

    // P -> bf16 -> per-wave LDS, re-read in A-fragment layout
    uint16_t* pw = sP[w];
#pragma unroll
    for (int ct = 0; ct < 4; ++ct)
#pragma unroll
      for (int r = 0; r < 4; ++r)
        pw[(lq * 4 + r) * 64 + ct * 16 + lr] = f2bf(accS[ct][r]);

#pragma unroll
    for (int js = 0; js < 2; ++js) {
      bf16x8 ap = *(const bf16x8*)(pw + lr * 64 + js * 32 + lq * 8);
#pragma unroll
      for (int dt = 0; dt < 8; ++dt) {
        bf16x8 bv = *(const bf16x8*)(sVT + (dt * 16 + lr) * 64 + js * 32 + lq * 8);
        accO[dt] = __builtin_amdgcn_mfma_f32_16x16x32_bf16(ap, bv, accO[dt], 0, 0, 0);
      }
    }
    ksrc += 64 * 128;
    vsrc += 64;
  }

  float invL[4];
#pragma unroll
  for (int r = 0; r < 4; ++r) invL[r] = 1.f / L[r];
#pragma unroll
  for (int dt = 0; dt < 8; ++dt)
#pragma unroll
    for (int r = 0; r < 4; ++r) {
      const int p = q0 + w * 16 + lq * 4 + r;
      o_r[(size_t)p * E_DIM + h * D_DIM + dt * 16 + lr] = f2bf(accO[dt][r] * invL[r]);
    }
}

extern "C" void kernel_launch(void* const* d_in, const int* in_sizes, int n_in,
                              void* d_out, int out_size, void* d_ws, size_t ws_size,
                              hipStream_t stream) {
  const float* x     = (const float*)d_in[0];
  const float* fcos  = (const float*)d_in[1];
  const float* fsin  = (const float*)d_in[2];
  const float* w_in  = (const float*)d_in[3];
  const float* w_out = (const float*)d_in[4];
  float* out = (float*)d_out;

  char* ws = (char*)d_ws;
  size_t off = 0;
  uint16_t* w_inT  = (uint16_t*)(ws + off); off += (size_t)QKV_N * E_DIM * 2;      // 3072x2048 bf16
  uint16_t* w_outT = (uint16_t*)(ws + off); off += (size_t)E_DIM * E_DIM * 2;      // 2048x2048 bf16
  uint16_t* qkv    = (uint16_t*)(ws + off); off += (size_t)S_LEN * QKV_N * 2;      // 4096x3072 bf16
  uint16_t* q_r    = (uint16_t*)(ws + off); off += (size_t)H_NUM * S_LEN * D_DIM * 2;
  uint16_t* k_r    = (uint16_t*)(ws + off); off += (size_t)G_NUM * S_LEN * D_DIM * 2;
  uint16_t* v_t    = (uint16_t*)(ws + off); off += (size_t)G_NUM * D_DIM * S_LEN * 2;
  uint16_t* o_r    = (uint16_t*)(ws + off); off += (size_t)S_LEN * E_DIM * 2;
  // x_bf aliases o_r: x_bf is consumed by gemm1 before attn writes o_r (stream-ordered).
  uint16_t* x_bf   = o_r;  // 4096x2048 bf16, same size as o_r

  // edge conversions: fp32 -> bf16
  conv_f2b<<<(S_LEN * E_DIM) / (256 * 8), 256, 0, stream>>>(x, x_bf);
  transpose_f2b<<<dim3(QKV_N / 64, E_DIM / 64), 256, 0, stream>>>(w_in, w_inT, QKV_N, E_DIM);
  transpose_f2b<<<dim3(E_DIM / 64, E_DIM / 64), 256, 0, stream>>>(w_out, w_outT, E_DIM, E_DIM);
  // qkv = x @ w_in  (bf16 out)
  gemm_bt<<<dim3(S_LEN / 128, QKV_N / 128), 256, 0, stream>>>(x_bf, w_inT, qkv, nullptr, S_LEN, QKV_N, E_DIM);
  // rope q,k ; transpose v
  rope_qk<<<(S_LEN * 1280) / 256, 256, 0, stream>>>(qkv, fcos, fsin, q_r, k_r);
  transpose_bf16<<<dim3(512 / 64, S_LEN / 64), 256, 0, stream>>>(qkv + 2560, v_t, QKV_N, S_LEN);
  // attention
  attn_kernel<<<dim3(S_LEN / 64, H_NUM), 256, 0, stream>>>(q_r, k_r, v_t, o_r);
  // out = o @ w_out  (fp32 out)
  gemm_bt<<<dim3(S_LEN / 128, E_DIM / 128), 256, 0, stream>>>(o_r, w_outT, nullptr, out, S_LEN, E_DIM, E_DIM);
}

// Round 3
// 266.322 us; speedup vs baseline: 1.1958x; 1.1958x over previous
//
#include <hip/hip_runtime.h>
#include <stdint.h>

using bf16x8 = __attribute__((ext_vector_type(8))) __bf16;
using f32x4  = __attribute__((ext_vector_type(4))) float;
using u16x8  = __attribute__((ext_vector_type(8))) uint16_t;

#define S_LEN 4096
#define E_DIM 2048
#define D_DIM 128
#define H_NUM 16
#define G_NUM 4
#define QKV_N 3072
#define SCALE 0.08838834764831845f

__device__ inline float bf2f(uint16_t b) {
  union { uint32_t u; float f; } v; v.u = ((uint32_t)b) << 16; return v.f;
}
__device__ inline uint16_t f2bf(float f) {
  union { float f; uint32_t u; } v; v.f = f;
  uint32_t u = v.u + 0x7FFFu + ((v.u >> 16) & 1u);
  return (uint16_t)(u >> 16);
}
__device__ inline void gload_lds16(const void* g, void* l) {
  __builtin_amdgcn_global_load_lds((const __attribute__((address_space(1))) void*)g,
                                   (__attribute__((address_space(3))) void*)l, 16, 0, 0);
}

// ---------------- fp32 -> bf16 convert (8 elems/thread) ----------------
__global__ __launch_bounds__(256) void conv_f2b(const float* __restrict__ in,
                                                uint16_t* __restrict__ out) {
  const size_t i = ((size_t)blockIdx.x * 256 + threadIdx.x) * 8;
  float4 a = *(const float4*)(in + i);
  float4 b = *(const float4*)(in + i + 4);
  u16x8 o;
  o[0] = f2bf(a.x); o[1] = f2bf(a.y); o[2] = f2bf(a.z); o[3] = f2bf(a.w);
  o[4] = f2bf(b.x); o[5] = f2bf(b.y); o[6] = f2bf(b.z); o[7] = f2bf(b.w);
  *(u16x8*)(out + i) = o;
}

// ---------------- transpose fp32 -> bf16: out[c][r] = bf16(in[r][c]) ----------------
__global__ __launch_bounds__(256) void transpose_f2b(
    const float* __restrict__ in, uint16_t* __restrict__ out,
    int ldi, int ldo)
{
  __shared__ __align__(16) uint16_t tile[64][65];
  const int c0 = blockIdx.x * 64, r0 = blockIdx.y * 64;
  const int t = threadIdx.x;
#pragma unroll
  for (int i = 0; i < 16; ++i) {
    int idx = t + i * 256;
    int r = idx >> 6, c = idx & 63;
    tile[r][c] = f2bf(in[(size_t)(r0 + r) * ldi + c0 + c]);
  }
  __syncthreads();
#pragma unroll
  for (int i = 0; i < 16; ++i) {
    int idx = t + i * 256;
    int cc = idx >> 6, rr = idx & 63;
    out[(size_t)(c0 + cc) * ldo + r0 + rr] = tile[rr][cc];
  }
}

// ---------------- transpose bf16 -> bf16 (for V) ----------------
__global__ __launch_bounds__(256) void transpose_bf16(
    const uint16_t* __restrict__ in, uint16_t* __restrict__ out,
    int ldi, int ldo)
{
  __shared__ __align__(16) uint16_t tile[64][65];
  const int c0 = blockIdx.x * 64, r0 = blockIdx.y * 64;
  const int t = threadIdx.x;
#pragma unroll
  for (int i = 0; i < 16; ++i) {
    int idx = t + i * 256;
    int r = idx >> 6, c = idx & 63;
    tile[r][c] = in[(size_t)(r0 + r) * ldi + c0 + c];
  }
  __syncthreads();
#pragma unroll
  for (int i = 0; i < 16; ++i) {
    int idx = t + i * 256;
    int cc = idx >> 6, rr = idx & 63;
    out[(size_t)(c0 + cc) * ldo + r0 + rr] = tile[rr][cc];
  }
}

// ---------------- GEMM: C = A[M][K](bf16) * Bt[N][K]^T(bf16), f32 acc ----------------
// 1D grid with XCD-aware swizzle (requires gridDim.x % 8 == 0).
__global__ __launch_bounds__(256) void gemm_bt(
    const uint16_t* __restrict__ A, const uint16_t* __restrict__ Bt,
    uint16_t* __restrict__ Cb, float* __restrict__ Cf, int M, int N, int K, int nwgm)
{
  __shared__ __align__(16) uint16_t sA[128 * 32];
  __shared__ __align__(16) uint16_t sB[128 * 32];
  const int nwg = gridDim.x;
  const int id = (blockIdx.x & 7) * (nwg >> 3) + (blockIdx.x >> 3);  // XCD swizzle
  const int m0 = (id % nwgm) * 128, n0 = (id / nwgm) * 128;
  const int tid = threadIdx.x, w = tid >> 6, lane = tid & 63;
  const int lr = lane & 15, lq = lane >> 4;
  const int wr = w >> 1, wc = w & 1;

  f32x4 acc[4][4];
#pragma unroll
  for (int i = 0; i < 4; ++i)
#pragma unroll
    for (int j = 0; j < 4; ++j) acc[i][j] = (f32x4){0.f, 0.f, 0.f, 0.f};

  const int nk = K >> 5;
  const int colb = (lane & 3) << 4;           // byte col within 64B row
  const int rbase0 = w * 32 + (lane >> 2);    // staging row for this lane
  const char* gA0 = (const char*)A + ((size_t)(m0 + rbase0) * K) * 2 + colb;
  const char* gA1 = (const char*)A + ((size_t)(m0 + rbase0 + 16) * K) * 2 + colb;
  const char* gB0 = (const char*)Bt + ((size_t)(n0 + rbase0) * K) * 2 + colb;
  const char* gB1 = (const char*)Bt + ((size_t)(n0 + rbase0 + 16) * K) * 2 + colb;
  char* lA0 = (char*)sA + (w * 2) * 1024;
  char* lA1 = (char*)sA + (w * 2 + 1) * 1024;
  char* lB0 = (char*)sB + (w * 2) * 1024;
  char* lB1 = (char*)sB + (w * 2 + 1) * 1024;

  for (int kt = 0; kt < nk; ++kt) {
    __syncthreads();
    const size_t ko = (size_t)kt * 64;  // 32 elems * 2B
    gload_lds16(gA0 + ko, lA0);
    gload_lds16(gA1 + ko, lA1);
    gload_lds16(gB0 + ko, lB0);
    gload_lds16(gB1 + ko, lB1);
    asm volatile("s_waitcnt vmcnt(0)" ::: "memory");
    __syncthreads();

    bf16x8 af[4], bfj[4];
#pragma unroll
    for (int i = 0; i < 4; ++i) af[i] = *(const bf16x8*)(sA + (wr * 64 + i * 16 + lr) * 32 + lq * 8);
#pragma unroll
    for (int j = 0; j < 4; ++j) bfj[j] = *(const bf16x8*)(sB + (wc * 64 + j * 16 + lr) * 32 + lq * 8);
#pragma unroll
    for (int i = 0; i < 4; ++i)
#pragma unroll
      for (int j = 0; j < 4; ++j)
        acc[i][j] = __builtin_amdgcn_mfma_f32_16x16x32_bf16(af[i], bfj[j], acc[i][j], 0, 0, 0);
  }

  if (Cf) {
#pragma unroll
    for (int i = 0; i < 4; ++i)
#pragma unroll
      for (int j = 0; j < 4; ++j)
#pragma unroll
        for (int r = 0; r < 4; ++r)
          Cf[(size_t)(m0 + wr * 64 + i * 16 + lq * 4 + r) * N + n0 + wc * 64 + j * 16 + lr] =
              acc[i][j][r];
  } else {
#pragma unroll
    for (int i = 0; i < 4; ++i)
#pragma unroll
      for (int j = 0; j < 4; ++j)
#pragma unroll
        for (int r = 0; r < 4; ++r)
          Cb[(size_t)(m0 + wr * 64 + i * 16 + lq * 4 + r) * N + n0 + wc * 64 + j * 16 + lr] =
              f2bf(acc[i][j][r]);
  }
}

// ---------------- RoPE + rearrange for q,k (cos/sin are fp32) ----------------
__global__ __launch_bounds__(256) void rope_qk(
    const uint16_t* __restrict__ qkv, const float* __restrict__ cosb,
    const float* __restrict__ sinb, uint16_t* __restrict__ q_r, uint16_t* __restrict__ k_r)
{
  const int idx = blockIdx.x * 256 + threadIdx.x;  // < 4096*1280
  const int s = idx / 1280;
  const int pp = idx - s * 1280;
  const int c0 = pp << 1;
  const uint32_t xp = *(const uint32_t*)(qkv + (size_t)s * QKV_N + c0);
  const float xe = bf2f((uint16_t)xp), xo = bf2f((uint16_t)(xp >> 16));
  const int dloc = c0 & 127;
  const int dd = dloc >> 1;
  const float cf = cosb[s * 64 + dd];
  const float sf = sinb[s * 64 + dd];
  float oe = xe * cf - xo * sf;
  float oo = xe * sf + xo * cf;
  uint16_t* dst;
  if (c0 < E_DIM) {
    oe *= SCALE; oo *= SCALE;                 // fold 1/sqrt(D) into q
    const int h = c0 >> 7;
    dst = q_r + ((size_t)h * S_LEN + s) * D_DIM + dloc;
  } else {
    const int g = (c0 - E_DIM) >> 7;
    dst = k_r + ((size_t)g * S_LEN + s) * D_DIM + dloc;
  }
  *(uint32_t*)dst = (uint32_t)f2bf(oe) | ((uint32_t)f2bf(oo) << 16);
}

// ---------------- flash attention, window [p-1024, p] ----------------
// XOR-swizzled LDS (T2) + double-buffered 2-phase staging (T3-min).
// Swizzle: byte_in_row ^= ((row&7)<<4). gload_lds writes linearly, so the
// swizzle is pre-applied to the per-lane GLOBAL source address (rule #21).
__global__ __launch_bounds__(256) void attn_kernel(
    const uint16_t* __restrict__ q_r, const uint16_t* __restrict__ k_r,
    const uint16_t* __restrict__ v_t, uint16_t* __restrict__ o_r)
{
  __shared__ __align__(16) uint16_t sK[2][64 * 128];   // [key][d], swizzled
  __shared__ __align__(16) uint16_t sVT[2][128 * 64];  // [d][key], swizzled
  __shared__ __align__(16) uint16_t sP[4][1024];       // per-wave [16][64], swizzled
  const int h = blockIdx.y, g = h >> 2;
  const int q0 = blockIdx.x * 64;
  const int tid = threadIdx.x, w = tid >> 6, lane = tid & 63;
  const int lr = lane & 15, lq = lane >> 4;
  const int swz = (lr & 7) << 3;  // element-index XOR for swizzled reads

  bf16x8 aq[4];
  {
    const uint16_t* qb = q_r + ((size_t)h * S_LEN + q0 + w * 16 + lr) * D_DIM + lq * 8;
#pragma unroll
    for (int ks = 0; ks < 4; ++ks) aq[ks] = *(const bf16x8*)(qb + ks * 32);
  }
  f32x4 accO[8];
#pragma unroll
  for (int dt = 0; dt < 8; ++dt) accO[dt] = (f32x4){0.f, 0.f, 0.f, 0.f};
  float M[4], L[4];
#pragma unroll
  for (int r = 0; r < 4; ++r) { M[r] = -1e30f; L[r] = 0.f; }

  const int jstart = (q0 >= 1024) ? (q0 - 1024) : 0;
  const int nt = (q0 + 64 - jstart) >> 6;
  const char* kb = (const char*)(k_r + ((size_t)g * S_LEN + jstart) * D_DIM);
  const char* vb = (const char*)(v_t + (size_t)g * D_DIM * S_LEN + jstart);

  // per-lane staging geometry (pre-swizzled global sources)
  const int kc_row = lane >> 4;                         // row within 4-row K chunk
  const int k_scol0 = (lane & 15) << 4;                 // linear byte col (K)
  const int v_scol = (((lane & 7) ^ (lane >> 3)) << 4); // swizzled byte col (V)
  const int v_row = lane >> 3;                          // row within 8-row V chunk

#define STAGE_KV(buf, tt)                                                              \
  {                                                                                    \
    const char* kt_ = kb + (size_t)(tt) * 16384;                                       \
    const char* vt_ = vb + (size_t)(tt) * 128;                                         \
    _Pragma("unroll")                                                                  \
    for (int it = 0; it < 4; ++it) {                                                   \
      const int c = w * 4 + it;                                                        \
      const int krow = c * 4 + kc_row;                                                 \
      const int kscol = k_scol0 ^ ((krow & 7) << 4);                                   \
      gload_lds16(kt_ + krow * 256 + kscol, (char*)sK[buf] + c * 1024 + lane * 16);    \
      const int vrow = c * 8 + v_row;                                                  \
      gload_lds16(vt_ + (size_t)vrow * (S_LEN * 2) + v_scol,                           \
                  (char*)sVT[buf] + c * 1024 + lane * 16);                             \
    }                                                                                  \
  }

  STAGE_KV(0, 0)
  __syncthreads();

  for (int t = 0; t < nt; ++t) {
    const int b = t & 1;
    if (t + 1 < nt) STAGE_KV(b ^ 1, t + 1)
    const int j0 = jstart + t * 64;
    const uint16_t* Kb = sK[b];
    const uint16_t* Vb = sVT[b];

    // QK^T : accS[ct] rows m=lq*4+r, cols j0+ct*16+lr
    f32x4 accS[4];
#pragma unroll
    for (int ct = 0; ct < 4; ++ct) {
      accS[ct] = (f32x4){0.f, 0.f, 0.f, 0.f};
#pragma unroll
      for (int ks = 0; ks < 4; ++ks) {
        bf16x8 bk = *(const bf16x8*)(Kb + (ct * 16 + lr) * 128 + ((ks * 32 + lq * 8) ^ swz));
        accS[ct] = __builtin_amdgcn_mfma_f32_16x16x32_bf16(aq[ks], bk, accS[ct], 0, 0, 0);
      }
    }

    const int pbase = q0 + w * 16 + lq * 4;
    float alpha[4];
#pragma unroll
    for (int r = 0; r < 4; ++r) {
      const int p = pbase + r;
      float mx = -1e30f;
#pragma unroll
      for (int ct = 0; ct < 4; ++ct) {
        const int j = j0 + ct * 16 + lr;
        float sc = accS[ct][r];
        const bool ok = (j <= p) && (j + 1024 >= p);
        sc = ok ? sc : -1e30f;
        accS[ct][r] = sc;
        mx = fmaxf(mx, sc);
      }
#pragma unroll
      for (int off = 1; off < 16; off <<= 1) mx = fmaxf(mx, __shfl_xor(mx, off));
      const float Mn = fmaxf(M[r], mx);
      const float al = __expf(M[r] - Mn);
      float rs = 0.f;
#pragma unroll
      for (int ct = 0; ct < 4; ++ct) {
        const float pv = __expf(accS[ct][r] - Mn);
        accS[ct][r] = pv;
        rs += pv;
      }
#pragma unroll
      for (int off = 1; off < 16; off <<= 1) rs += __shfl_xor(rs, off);
      L[r] = L[r] * al + rs;
      M[r] = Mn;
      alpha[r] = al;
    }
#pragma unroll
    for (int dt = 0; dt < 8; ++dt)
#pragma unroll
      for (int r = 0; r < 4; ++r) accO[dt][r] *= alpha[r];

    // P -> bf16 -> per-wave LDS (swizzled), re-read in A-fragment layout
    uint16_t* pw = sP[w];
#pragma unroll
    for (int ct = 0; ct < 4; ++ct)
#pragma unroll
      for (int r = 0; r < 4; ++r) {
        const int prow = lq * 4 + r;
        pw[prow * 64 + ((ct * 16 + lr) ^ ((prow & 7) << 3))] = f2bf(accS[ct][r]);
      }

#pragma unroll
    for (int js = 0; js < 2; ++js) {
      bf16x8 ap = *(const bf16x8*)(pw + lr * 64 + ((js * 32 + lq * 8) ^ swz));
#pragma unroll
      for (int dt = 0; dt < 8; ++dt) {
        bf16x8 bv = *(const bf16x8*)(Vb + (dt * 16 + lr) * 64 + ((js * 32 + lq * 8) ^ swz));
        accO[dt] = __builtin_amdgcn_mfma_f32_16x16x32_bf16(ap, bv, accO[dt], 0, 0, 0);
      }
    }

    asm volatile("s_waitcnt vmcnt(0)" ::: "memory");
    __syncthreads();
  }

  float invL[4];
#pragma unroll
  for (int r = 0; r < 4; ++r) invL[r] = 1.f / L[r];
#pragma unroll
  for (int dt = 0; dt < 8; ++dt)
#pragma unroll
    for (int r = 0; r < 4; ++r) {
      const int p = q0 + w * 16 + lq * 4 + r;
      o_r[(size_t)p * E_DIM + h * D_DIM + dt * 16 + lr] = f2bf(accO[dt][r] * invL[r]);
    }
}

extern "C" void kernel_launch(void* const* d_in, const int* in_sizes, int n_in,
                              void* d_out, int out_size, void* d_ws, size_t ws_size,
                              hipStream_t stream) {
  const float* x     = (const float*)d_in[0];
  const float* fcos  = (const float*)d_in[1];
  const float* fsin  = (const float*)d_in[2];
  const float* w_in  = (const float*)d_in[3];
  const float* w_out = (const float*)d_in[4];
  float* out = (float*)d_out;

  char* ws = (char*)d_ws;
  size_t off = 0;
  uint16_t* w_inT  = (uint16_t*)(ws + off); off += (size_t)QKV_N * E_DIM * 2;      // 3072x2048 bf16
  uint16_t* w_outT = (uint16_t*)(ws + off); off += (size_t)E_DIM * E_DIM * 2;      // 2048x2048 bf16
  uint16_t* qkv    = (uint16_t*)(ws + off); off += (size_t)S_LEN * QKV_N * 2;      // 4096x3072 bf16
  uint16_t* q_r    = (uint16_t*)(ws + off); off += (size_t)H_NUM * S_LEN * D_DIM * 2;
  uint16_t* k_r    = (uint16_t*)(ws + off); off += (size_t)G_NUM * S_LEN * D_DIM * 2;
  uint16_t* v_t    = (uint16_t*)(ws + off); off += (size_t)G_NUM * D_DIM * S_LEN * 2;
  uint16_t* o_r    = (uint16_t*)(ws + off); off += (size_t)S_LEN * E_DIM * 2;
  // x_bf aliases o_r: x_bf is consumed by gemm1 before attn writes o_r (stream-ordered).
  uint16_t* x_bf   = o_r;  // 4096x2048 bf16, same size as o_r

  // edge conversions: fp32 -> bf16
  conv_f2b<<<(S_LEN * E_DIM) / (256 * 8), 256, 0, stream>>>(x, x_bf);
  transpose_f2b<<<dim3(QKV_N / 64, E_DIM / 64), 256, 0, stream>>>(w_in, w_inT, QKV_N, E_DIM);
  transpose_f2b<<<dim3(E_DIM / 64, E_DIM / 64), 256, 0, stream>>>(w_out, w_outT, E_DIM, E_DIM);
  // qkv = x @ w_in  (bf16 out); grid flattened, %8==0 for XCD swizzle
  gemm_bt<<<(S_LEN / 128) * (QKV_N / 128), 256, 0, stream>>>(x_bf, w_inT, qkv, nullptr,
                                                             S_LEN, QKV_N, E_DIM, S_LEN / 128);
  // rope q,k ; transpose v
  rope_qk<<<(S_LEN * 1280) / 256, 256, 0, stream>>>(qkv, fcos, fsin, q_r, k_r);
  transpose_bf16<<<dim3(512 / 64, S_LEN / 64), 256, 0, stream>>>(qkv + 2560, v_t, QKV_N, S_LEN);
  // attention
  attn_kernel<<<dim3(S_LEN / 64, H_NUM), 256, 0, stream>>>(q_r, k_r, v_t, o_r);
  // out = o @ w_out  (fp32 out)
  gemm_bt<<<(S_LEN / 128) * (E_DIM / 128), 256, 0, stream>>>(o_r, w_outT, nullptr, out,
                                                             S_LEN, E_DIM, E_DIM, S_LEN / 128);
}

// Round 4
// 248.892 us; speedup vs baseline: 1.2796x; 1.0700x over previous
//
#include <hip/hip_runtime.h>
#include <stdint.h>

using bf16x8 = __attribute__((ext_vector_type(8))) __bf16;
using f32x4  = __attribute__((ext_vector_type(4))) float;
using u16x8  = __attribute__((ext_vector_type(8))) uint16_t;

#define S_LEN 4096
#define E_DIM 2048
#define D_DIM 128
#define H_NUM 16
#define G_NUM 4
#define QKV_N 3072
#define SCALE 0.08838834764831845f

__device__ inline float bf2f(uint16_t b) {
  union { uint32_t u; float f; } v; v.u = ((uint32_t)b) << 16; return v.f;
}
__device__ inline uint16_t f2bf(float f) {
  union { float f; uint32_t u; } v; v.f = f;
  uint32_t u = v.u + 0x7FFFu + ((v.u >> 16) & 1u);
  return (uint16_t)(u >> 16);
}
__device__ inline uint16_t f2bf_fast(float f) {  // round-half-up (hot path)
  union { float f; uint32_t u; } v; v.f = f;
  return (uint16_t)((v.u + 0x8000u) >> 16);
}
__device__ inline void gload_lds16(const void* g, void* l) {
  __builtin_amdgcn_global_load_lds((const __attribute__((address_space(1))) void*)g,
                                   (__attribute__((address_space(3))) void*)l, 16, 0, 0);
}

// ---------------- fp32 -> bf16 convert (8 elems/thread) ----------------
__global__ __launch_bounds__(256) void conv_f2b(const float* __restrict__ in,
                                                uint16_t* __restrict__ out) {
  const size_t i = ((size_t)blockIdx.x * 256 + threadIdx.x) * 8;
  float4 a = *(const float4*)(in + i);
  float4 b = *(const float4*)(in + i + 4);
  u16x8 o;
  o[0] = f2bf(a.x); o[1] = f2bf(a.y); o[2] = f2bf(a.z); o[3] = f2bf(a.w);
  o[4] = f2bf(b.x); o[5] = f2bf(b.y); o[6] = f2bf(b.z); o[7] = f2bf(b.w);
  *(u16x8*)(out + i) = o;
}

// ---------------- transpose fp32 -> bf16: out[c][r] = bf16(in[r][c]) ----------------
__global__ __launch_bounds__(256) void transpose_f2b(
    const float* __restrict__ in, uint16_t* __restrict__ out,
    int ldi, int ldo)
{
  __shared__ __align__(16) uint16_t tile[64][65];
  const int c0 = blockIdx.x * 64, r0 = blockIdx.y * 64;
  const int t = threadIdx.x;
#pragma unroll
  for (int i = 0; i < 16; ++i) {
    int idx = t + i * 256;
    int r = idx >> 6, c = idx & 63;
    tile[r][c] = f2bf(in[(size_t)(r0 + r) * ldi + c0 + c]);
  }
  __syncthreads();
#pragma unroll
  for (int i = 0; i < 16; ++i) {
    int idx = t + i * 256;
    int cc = idx >> 6, rr = idx & 63;
    out[(size_t)(c0 + cc) * ldo + r0 + rr] = tile[rr][cc];
  }
}

// ---------------- transpose bf16 -> bf16 (for V) ----------------
__global__ __launch_bounds__(256) void transpose_bf16(
    const uint16_t* __restrict__ in, uint16_t* __restrict__ out,
    int ldi, int ldo)
{
  __shared__ __align__(16) uint16_t tile[64][65];
  const int c0 = blockIdx.x * 64, r0 = blockIdx.y * 64;
  const int t = threadIdx.x;
#pragma unroll
  for (int i = 0; i < 16; ++i) {
    int idx = t + i * 256;
    int r = idx >> 6, c = idx & 63;
    tile[r][c] = in[(size_t)(r0 + r) * ldi + c0 + c];
  }
  __syncthreads();
#pragma unroll
  for (int i = 0; i < 16; ++i) {
    int idx = t + i * 256;
    int cc = idx >> 6, rr = idx & 63;
    out[(size_t)(c0 + cc) * ldo + r0 + rr] = tile[rr][cc];
  }
}

// ---------------- GEMM: C = A[M][K](bf16) * Bt[N][K]^T(bf16), f32 acc ----------------
// 1D grid with XCD-aware swizzle (requires gridDim.x % 8 == 0).
__global__ __launch_bounds__(256) void gemm_bt(
    const uint16_t* __restrict__ A, const uint16_t* __restrict__ Bt,
    uint16_t* __restrict__ Cb, float* __restrict__ Cf, int M, int N, int K, int nwgm)
{
  __shared__ __align__(16) uint16_t sA[128 * 32];
  __shared__ __align__(16) uint16_t sB[128 * 32];
  const int nwg = gridDim.x;
  const int id = (blockIdx.x & 7) * (nwg >> 3) + (blockIdx.x >> 3);  // XCD swizzle
  const int m0 = (id % nwgm) * 128, n0 = (id / nwgm) * 128;
  const int tid = threadIdx.x, w = tid >> 6, lane = tid & 63;
  const int lr = lane & 15, lq = lane >> 4;
  const int wr = w >> 1, wc = w & 1;

  f32x4 acc[4][4];
#pragma unroll
  for (int i = 0; i < 4; ++i)
#pragma unroll
    for (int j = 0; j < 4; ++j) acc[i][j] = (f32x4){0.f, 0.f, 0.f, 0.f};

  const int nk = K >> 5;
  const int colb = (lane & 3) << 4;           // byte col within 64B row
  const int rbase0 = w * 32 + (lane >> 2);    // staging row for this lane
  const char* gA0 = (const char*)A + ((size_t)(m0 + rbase0) * K) * 2 + colb;
  const char* gA1 = (const char*)A + ((size_t)(m0 + rbase0 + 16) * K) * 2 + colb;
  const char* gB0 = (const char*)Bt + ((size_t)(n0 + rbase0) * K) * 2 + colb;
  const char* gB1 = (const char*)Bt + ((size_t)(n0 + rbase0 + 16) * K) * 2 + colb;
  char* lA0 = (char*)sA + (w * 2) * 1024;
  char* lA1 = (char*)sA + (w * 2 + 1) * 1024;
  char* lB0 = (char*)sB + (w * 2) * 1024;
  char* lB1 = (char*)sB + (w * 2 + 1) * 1024;

  for (int kt = 0; kt < nk; ++kt) {
    __syncthreads();
    const size_t ko = (size_t)kt * 64;  // 32 elems * 2B
    gload_lds16(gA0 + ko, lA0);
    gload_lds16(gA1 + ko, lA1);
    gload_lds16(gB0 + ko, lB0);
    gload_lds16(gB1 + ko, lB1);
    asm volatile("s_waitcnt vmcnt(0)" ::: "memory");
    __syncthreads();

    bf16x8 af[4], bfj[4];
#pragma unroll
    for (int i = 0; i < 4; ++i) af[i] = *(const bf16x8*)(sA + (wr * 64 + i * 16 + lr) * 32 + lq * 8);
#pragma unroll
    for (int j = 0; j < 4; ++j) bfj[j] = *(const bf16x8*)(sB + (wc * 64 + j * 16 + lr) * 32 + lq * 8);
#pragma unroll
    for (int i = 0; i < 4; ++i)
#pragma unroll
      for (int j = 0; j < 4; ++j)
        acc[i][j] = __builtin_amdgcn_mfma_f32_16x16x32_bf16(af[i], bfj[j], acc[i][j], 0, 0, 0);
  }

  if (Cf) {
#pragma unroll
    for (int i = 0; i < 4; ++i)
#pragma unroll
      for (int j = 0; j < 4; ++j)
#pragma unroll
        for (int r = 0; r < 4; ++r)
          Cf[(size_t)(m0 + wr * 64 + i * 16 + lq * 4 + r) * N + n0 + wc * 64 + j * 16 + lr] =
              acc[i][j][r];
  } else {
#pragma unroll
    for (int i = 0; i < 4; ++i)
#pragma unroll
      for (int j = 0; j < 4; ++j)
#pragma unroll
        for (int r = 0; r < 4; ++r)
          Cb[(size_t)(m0 + wr * 64 + i * 16 + lq * 4 + r) * N + n0 + wc * 64 + j * 16 + lr] =
              f2bf(acc[i][j][r]);
  }
}

// ---------------- RoPE + rearrange for q,k (cos/sin are fp32) ----------------
__global__ __launch_bounds__(256) void rope_qk(
    const uint16_t* __restrict__ qkv, const float* __restrict__ cosb,
    const float* __restrict__ sinb, uint16_t* __restrict__ q_r, uint16_t* __restrict__ k_r)
{
  const int idx = blockIdx.x * 256 + threadIdx.x;  // < 4096*1280
  const int s = idx / 1280;
  const int pp = idx - s * 1280;
  const int c0 = pp << 1;
  const uint32_t xp = *(const uint32_t*)(qkv + (size_t)s * QKV_N + c0);
  const float xe = bf2f((uint16_t)xp), xo = bf2f((uint16_t)(xp >> 16));
  const int dloc = c0 & 127;
  const int dd = dloc >> 1;
  const float cf = cosb[s * 64 + dd];
  const float sf = sinb[s * 64 + dd];
  float oe = xe * cf - xo * sf;
  float oo = xe * sf + xo * cf;
  uint16_t* dst;
  if (c0 < E_DIM) {
    oe *= SCALE; oo *= SCALE;                 // fold 1/sqrt(D) into q
    const int h = c0 >> 7;
    dst = q_r + ((size_t)h * S_LEN + s) * D_DIM + dloc;
  } else {
    const int g = (c0 - E_DIM) >> 7;
    dst = k_r + ((size_t)g * S_LEN + s) * D_DIM + dloc;
  }
  *(uint32_t*)dst = (uint32_t)f2bf(oe) | ((uint32_t)f2bf(oo) << 16);
}

// ---------------- flash attention, window [p-1024, p] ----------------
// QBLK=128, 8 waves x 16 rows. T2 XOR-swizzled LDS, double-buffered staging,
// mask-specialized tiles, per-wave tile skip, exact defer-rescale, setprio.
__global__ __launch_bounds__(512, 4) void attn_kernel(
    const uint16_t* __restrict__ q_r, const uint16_t* __restrict__ k_r,
    const uint16_t* __restrict__ v_t, uint16_t* __restrict__ o_r)
{
  __shared__ __align__(16) uint16_t sK[2][64 * 128];   // [key][d], swizzled
  __shared__ __align__(16) uint16_t sVT[2][128 * 64];  // [d][key], swizzled
  __shared__ __align__(16) uint16_t sP[8][1024];       // per-wave [16][64], swizzled
  const int h = blockIdx.y, g = h >> 2;
  const int q0 = blockIdx.x * 128;
  const int tid = threadIdx.x, w = tid >> 6, lane = tid & 63;
  const int lr = lane & 15, lq = lane >> 4;
  const int swz = (lr & 7) << 3;  // element-index XOR for swizzled reads

  const int pmin = q0 + w * 16, pmax = pmin + 15;

  bf16x8 aq[4];
  {
    const uint16_t* qb = q_r + ((size_t)h * S_LEN + pmin + lr) * D_DIM + lq * 8;
#pragma unroll
    for (int ks = 0; ks < 4; ++ks) aq[ks] = *(const bf16x8*)(qb + ks * 32);
  }
  f32x4 accO[8];
#pragma unroll
  for (int dt = 0; dt < 8; ++dt) accO[dt] = (f32x4){0.f, 0.f, 0.f, 0.f};
  float M[4], L[4];
#pragma unroll
  for (int r = 0; r < 4; ++r) { M[r] = -1e30f; L[r] = 0.f; }

  const int jstart = (q0 >= 1024) ? (q0 - 1024) : 0;
  const int nt = (q0 + 128 - jstart) >> 6;
  const char* kb = (const char*)(k_r + ((size_t)g * S_LEN + jstart) * D_DIM);
  const char* vb = (const char*)(v_t + (size_t)g * D_DIM * S_LEN + jstart);

  // per-lane staging geometry (pre-swizzled global sources; 2 chunks/wave each)
  const int kc_row = lane >> 4;                         // row within 4-row K chunk
  const int k_col0 = (lane & 15) << 4;                  // linear byte col (K)
  const int v_scol = (((lane & 7) ^ (lane >> 3)) << 4); // swizzled byte col (V)
  const int v_row = lane >> 3;                          // row within 8-row V chunk

#define STAGE_KV(buf, tt)                                                              \
  {                                                                                    \
    const char* kt_ = kb + (size_t)(tt) * 16384;                                       \
    const char* vt_ = vb + (size_t)(tt) * 128;                                         \
    _Pragma("unroll")                                                                  \
    for (int it = 0; it < 2; ++it) {                                                   \
      const int c = w * 2 + it;                                                        \
      const int krow = c * 4 + kc_row;                                                 \
      const int kscol = k_col0 ^ ((krow & 7) << 4);                                    \
      gload_lds16(kt_ + krow * 256 + kscol, (char*)sK[buf] + c * 1024 + lane * 16);    \
      const int vrow = c * 8 + v_row;                                                  \
      gload_lds16(vt_ + (size_t)vrow * (S_LEN * 2) + v_scol,                           \
                  (char*)sVT[buf] + c * 1024 + lane * 16);                             \
    }                                                                                  \
  }

  STAGE_KV(0, 0)
  asm volatile("s_waitcnt vmcnt(0)" ::: "memory");
  __syncthreads();

  for (int t = 0; t < nt; ++t) {
    const int b = t & 1;
    if (t + 1 < nt) STAGE_KV(b ^ 1, t + 1)
    const int j0 = jstart + t * 64;
    const uint16_t* Kb = sK[b];
    const uint16_t* Vb = sVT[b];

    // wave-level tile skip: fully outside [pmin-1024, pmax]?
    const bool active = (j0 <= pmax) && (j0 + 63 + 1024 >= pmin);
    if (active) {
      // QK^T : accS[ct] rows m=lq*4+r, cols j0+ct*16+lr
      f32x4 accS[4];
      __builtin_amdgcn_s_setprio(1);
#pragma unroll
      for (int ct = 0; ct < 4; ++ct) {
        accS[ct] = (f32x4){0.f, 0.f, 0.f, 0.f};
#pragma unroll
        for (int ks = 0; ks < 4; ++ks) {
          bf16x8 bk = *(const bf16x8*)(Kb + (ct * 16 + lr) * 128 + ((ks * 32 + lq * 8) ^ swz));
          accS[ct] = __builtin_amdgcn_mfma_f32_16x16x32_bf16(aq[ks], bk, accS[ct], 0, 0, 0);
        }
      }
      __builtin_amdgcn_s_setprio(0);

      // mask only edge tiles (wave-uniform branch)
      const bool need_mask = (j0 + 63 > pmin) || (j0 < pmax - 1024);
      if (need_mask) {
#pragma unroll
        for (int ct = 0; ct < 4; ++ct) {
          const int j = j0 + ct * 16 + lr;
#pragma unroll
          for (int r = 0; r < 4; ++r) {
            const int p = pmin + lq * 4 + r;
            const bool ok = (j <= p) && (j + 1024 >= p);
            accS[ct][r] = ok ? accS[ct][r] : -1e30f;
          }
        }
      }

      // interleaved max-reduce (4 independent chains)
      float mx[4];
#pragma unroll
      for (int r = 0; r < 4; ++r)
        mx[r] = fmaxf(fmaxf(accS[0][r], accS[1][r]), fmaxf(accS[2][r], accS[3][r]));
#pragma unroll
      for (int off = 1; off < 16; off <<= 1)
#pragma unroll
        for (int r = 0; r < 4; ++r) mx[r] = fmaxf(mx[r], __shfl_xor(mx[r], off));

      // exact defer-rescale: only rescale when some lane's max grew
      const bool grow = (mx[0] > M[0]) | (mx[1] > M[1]) | (mx[2] > M[2]) | (mx[3] > M[3]);
      if (__any(grow)) {
#pragma unroll
        for (int r = 0; r < 4; ++r) {
          const float Mn = fmaxf(M[r], mx[r]);
          const float al = __expf(M[r] - Mn);
          M[r] = Mn;
          L[r] *= al;
#pragma unroll
          for (int dt = 0; dt < 8; ++dt) accO[dt][r] *= al;
        }
      }

      // probs + interleaved sum-reduce
      float rs[4];
#pragma unroll
      for (int r = 0; r < 4; ++r) {
        float s0 = 0.f;
#pragma unroll
        for (int ct = 0; ct < 4; ++ct) {
          const float pv = __expf(accS[ct][r] - M[r]);
          accS[ct][r] = pv;
          s0 += pv;
        }
        rs[r] = s0;
      }
#pragma unroll
      for (int off = 1; off < 16; off <<= 1)
#pragma unroll
        for (int r = 0; r < 4; ++r) rs[r] += __shfl_xor(rs[r], off);
#pragma unroll
      for (int r = 0; r < 4; ++r) L[r] += rs[r];

      // P -> bf16 -> per-wave LDS (swizzled), re-read in A-fragment layout
      uint16_t* pw = sP[w];
#pragma unroll
      for (int ct = 0; ct < 4; ++ct)
#pragma unroll
        for (int r = 0; r < 4; ++r) {
          const int prow = lq * 4 + r;
          pw[prow * 64 + ((ct * 16 + lr) ^ ((prow & 7) << 3))] = f2bf_fast(accS[ct][r]);
        }

      __builtin_amdgcn_s_setprio(1);
#pragma unroll
      for (int js = 0; js < 2; ++js) {
        bf16x8 ap = *(const bf16x8*)(pw + lr * 64 + ((js * 32 + lq * 8) ^ swz));
#pragma unroll
        for (int dt = 0; dt < 8; ++dt) {
          bf16x8 bv = *(const bf16x8*)(Vb + (dt * 16 + lr) * 64 + ((js * 32 + lq * 8) ^ swz));
          accO[dt] = __builtin_amdgcn_mfma_f32_16x16x32_bf16(ap, bv, accO[dt], 0, 0, 0);
        }
      }
      __builtin_amdgcn_s_setprio(0);
    }

    asm volatile("s_waitcnt vmcnt(0)" ::: "memory");
    __syncthreads();
  }

  float invL[4];
#pragma unroll
  for (int r = 0; r < 4; ++r) invL[r] = 1.f / L[r];
#pragma unroll
  for (int dt = 0; dt < 8; ++dt)
#pragma unroll
    for (int r = 0; r < 4; ++r) {
      const int p = pmin + lq * 4 + r;
      o_r[(size_t)p * E_DIM + h * D_DIM + dt * 16 + lr] = f2bf(accO[dt][r] * invL[r]);
    }
}

extern "C" void kernel_launch(void* const* d_in, const int* in_sizes, int n_in,
                              void* d_out, int out_size, void* d_ws, size_t ws_size,
                              hipStream_t stream) {
  const float* x     = (const float*)d_in[0];
  const float* fcos  = (const float*)d_in[1];
  const float* fsin  = (const float*)d_in[2];
  const float* w_in  = (const float*)d_in[3];
  const float* w_out = (const float*)d_in[4];
  float* out = (float*)d_out;

  char* ws = (char*)d_ws;
  size_t off = 0;
  uint16_t* w_inT  = (uint16_t*)(ws + off); off += (size_t)QKV_N * E_DIM * 2;      // 3072x2048 bf16
  uint16_t* w_outT = (uint16_t*)(ws + off); off += (size_t)E_DIM * E_DIM * 2;      // 2048x2048 bf16
  uint16_t* qkv    = (uint16_t*)(ws + off); off += (size_t)S_LEN * QKV_N * 2;      // 4096x3072 bf16
  uint16_t* q_r    = (uint16_t*)(ws + off); off += (size_t)H_NUM * S_LEN * D_DIM * 2;
  uint16_t* k_r    = (uint16_t*)(ws + off); off += (size_t)G_NUM * S_LEN * D_DIM * 2;
  uint16_t* v_t    = (uint16_t*)(ws + off); off += (size_t)G_NUM * D_DIM * S_LEN * 2;
  uint16_t* o_r    = (uint16_t*)(ws + off); off += (size_t)S_LEN * E_DIM * 2;
  // x_bf aliases o_r: x_bf is consumed by gemm1 before attn writes o_r (stream-ordered).
  uint16_t* x_bf   = o_r;  // 4096x2048 bf16, same size as o_r

  // edge conversions: fp32 -> bf16
  conv_f2b<<<(S_LEN * E_DIM) / (256 * 8), 256, 0, stream>>>(x, x_bf);
  transpose_f2b<<<dim3(QKV_N / 64, E_DIM / 64), 256, 0, stream>>>(w_in, w_inT, QKV_N, E_DIM);
  transpose_f2b<<<dim3(E_DIM / 64, E_DIM / 64), 256, 0, stream>>>(w_out, w_outT, E_DIM, E_DIM);
  // qkv = x @ w_in  (bf16 out); grid flattened, %8==0 for XCD swizzle
  gemm_bt<<<(S_LEN / 128) * (QKV_N / 128), 256, 0, stream>>>(x_bf, w_inT, qkv, nullptr,
                                                             S_LEN, QKV_N, E_DIM, S_LEN / 128);
  // rope q,k ; transpose v
  rope_qk<<<(S_LEN * 1280) / 256, 256, 0, stream>>>(qkv, fcos, fsin, q_r, k_r);
  transpose_bf16<<<dim3(512 / 64, S_LEN / 64), 256, 0, stream>>>(qkv + 2560, v_t, QKV_N, S_LEN);
  // attention (QBLK=128, 8 waves)
  attn_kernel<<<dim3(S_LEN / 128, H_NUM), 512, 0, stream>>>(q_r, k_r, v_t, o_r);
  // out = o @ w_out  (fp32 out)
  gemm_bt<<<(S_LEN / 128) * (E_DIM / 128), 256, 0, stream>>>(o_r, w_outT, nullptr, out,
                                                             S_LEN, E_DIM, E_DIM, S_LEN / 128);
}